// Round 7
// baseline (26835.339 us; speedup 1.0000x reference)
//
#include <hip/hip_runtime.h>
#include <hip/hip_bf16.h>
#include <cstdint>
#include <cstddef>

// ---------------------------------------------------------------------------
// HopfieldModel: z = x@W_enc; 4x { q <- softmax(2 q K^T) K } per network;
// out = log_softmax(relu(concat q) @ W_lin + b_lin)
//
// scan (fp16 MFMA, two passes per 1024-key chunk):
//   pass A: chunk-local per-query max (LDS atomicMax, block-shared).
//   pass B: emit packed (key<<16 | fp16 score) for s >= chunkmax - EMIT_MARGIN
//           into an LDS buffer (LDS atomics only), then flush to a FIXED
//           per-(query,chunk) global region + plain-store count.  NO global
//           atomics (round-6 lesson: 500K device-scope atomics on shared
//           cachelines ping-pong across the 8 non-coherent XCD L2s -> 35 MB
//           writeback, 192us latency-bound scan).
// Superset property: chunkmax <= globalmax, so every key within EMIT_MARGIN
// of the global max is emitted.  refine: gather segments, global max from
// STORED fp16 scores, filter to survivors within SEL_MARGIN, exact fp32
// re-score of survivors, exact softmax+PV.  Overflow (cnt>BLOCKCAP, ~1e-15)
// -> exact full-scan fallback for that query.
// ---------------------------------------------------------------------------

#define NNET 4
#define NQ   256
#define EDIM 128
#define NKEY 32768
#define ESTR 129              // embeddings row stride (col 128 dropped)
#define QT   32               // q rows per scan block
#define NCHUNK 32
#define KPC  (NKEY/NCHUNK)    // 1024 keys per chunk
#define SCAN_WAVES 4
#define KPW  (KPC/SCAN_WAVES) // 256 keys per wave
#define SLICES (KPW/16)       // 16 slices of 16 keys
#define SROW (QT/16)          // 2 row-tiles of 16 q rows
#define BLOCKCAP 32           // cand slots per (query, chunk); log2 = 5
#define EMIT_MARGIN 10.0f
#define SEL_MARGIN  9.5f

typedef _Float16 half8 __attribute__((ext_vector_type(8)));
typedef float f32x4v __attribute__((ext_vector_type(4)));

__device__ __forceinline__ float dec16(unsigned v) {
  _Float16 h = __builtin_bit_cast(_Float16, (unsigned short)(v & 0xFFFFu));
  return (float)h;
}
__device__ __forceinline__ unsigned pack16(int key, float s) {
  unsigned short hb = __builtin_bit_cast(unsigned short, (_Float16)s);
  return ((unsigned)key << 16) | (unsigned)hb;
}
__device__ __forceinline__ unsigned enc_f32(float f) {
  unsigned u = __float_as_uint(f);
  return (u & 0x80000000u) ? ~u : (u | 0x80000000u);  // order-preserving
}
__device__ __forceinline__ float dec_f32(unsigned e) {
  unsigned u = (e & 0x80000000u) ? (e & 0x7FFFFFFFu) : ~e;
  return __uint_as_float(u);
}

// --------------------------- encoder: z = x@We + be -------------------------
__global__ __launch_bounds__(128)
void enc_kernel(const float* __restrict__ x, const float* __restrict__ We,
                const float* __restrict__ be, float* __restrict__ q0) {
  const int b = blockIdx.x, tid = threadIdx.x;
  __shared__ float xs[784];
  for (int i = tid; i < 784; i += 128) xs[i] = x[b * 784 + i];
  __syncthreads();
  float acc = be[tid];
  for (int i = 0; i < 784; ++i) acc += xs[i] * We[i * EDIM + tid];
#pragma unroll
  for (int n = 0; n < NNET; ++n) q0[((size_t)n * NQ + b) * EDIM + tid] = acc;
}

// ------------------- keyprep: embeddings f32 -> fp16 (drop col 128) --------
typedef _Float16 half4v __attribute__((ext_vector_type(4)));
__global__ __launch_bounds__(256)
void keyprep_kernel(const float* __restrict__ emb, _Float16* __restrict__ kh) {
  const size_t quads = (size_t)NNET * NKEY * EDIM / 4;
  for (size_t i4 = (size_t)blockIdx.x * 256 + threadIdx.x; i4 < quads;
       i4 += (size_t)gridDim.x * 256) {
    const size_t row = i4 >> 5;
    const int col = (int)(i4 & 31) * 4;
    const float* src = emb + row * ESTR + col;
    half4v h;
#pragma unroll
    for (int j = 0; j < 4; ++j) h[j] = (_Float16)src[j];
    *(half4v*)(kh + i4 * 4) = h;
  }
}

// ------------------------------- scan --------------------------------------
// grid (128, 8): x = net*32+chunk, y = q-tile (32 rows).  256 threads =
// 4 waves, each wave owns 256 keys.  Same-x blocks land on one XCD (ids
// differ by multiples of 128 == 0 mod 8), so the 256KB key chunk is L2-hot.
template <bool F16K>
__global__ __launch_bounds__(SCAN_WAVES * 64)
void scan_kernel(const float* __restrict__ qcur, const float* __restrict__ emb,
                 const _Float16* __restrict__ keysh,
                 int* __restrict__ cntb, unsigned* __restrict__ cand) {
  const int nc = blockIdx.x;
  const int net = nc >> 5, chunk = nc & 31;
  const int qt = blockIdx.y;
  const int tid = threadIdx.x;
  const int lane = tid & 63, w = tid >> 6;
  const int g = lane >> 4, ln = lane & 15;

  __shared__ unsigned lmax[QT];
  __shared__ int lcnt[QT];
  __shared__ unsigned lbuf[QT][BLOCKCAP];
  if (tid < QT) { lmax[tid] = enc_f32(-3.4e38f); lcnt[tid] = 0; }

  // Q A-fragments (16x16x32: lane holds row m=lane&15, k = 8*(lane>>4)+j),
  // beta=2 folded into q.
  half8 aq[SROW][4];
  {
    const float* qb = qcur + ((size_t)net * NQ + qt * QT) * EDIM;
#pragma unroll
    for (int s = 0; s < SROW; ++s)
#pragma unroll
      for (int f = 0; f < 4; ++f) {
        const float* p = qb + (s * 16 + ln) * EDIM + f * 32 + g * 8;
        half8 h;
#pragma unroll
        for (int j = 0; j < 8; ++j) h[j] = (_Float16)(2.0f * p[j]);
        aq[s][f] = h;
      }
  }
  __syncthreads();

  const int key0 = chunk * KPC + w * KPW;

  auto loadB = [&](int sl, half8 bk[4]) {
    const size_t keyrow = (size_t)net * NKEY + key0 + sl * 16 + ln;
    if constexpr (F16K) {
      const _Float16* kp = keysh + keyrow * EDIM + g * 8;
#pragma unroll
      for (int f = 0; f < 4; ++f) bk[f] = *(const half8*)(kp + f * 32);
    } else {
      const float* kp = emb + keyrow * ESTR + g * 8;
#pragma unroll
      for (int f = 0; f < 4; ++f) {
        half8 h;
#pragma unroll
        for (int j = 0; j < 8; ++j) h[j] = (_Float16)kp[f * 32 + j];
        bk[f] = h;
      }
    }
  };

  // ---- pass A: chunk-local per-query max ----
  float rowmax[SROW * 4];
#pragma unroll
  for (int i = 0; i < SROW * 4; ++i) rowmax[i] = -3.4e38f;

  for (int sl = 0; sl < SLICES; ++sl) {
    half8 bk[4];
    loadB(sl, bk);
    f32x4v acc[SROW];
#pragma unroll
    for (int s = 0; s < SROW; ++s) acc[s] = f32x4v{0.f, 0.f, 0.f, 0.f};
#pragma unroll
    for (int f = 0; f < 4; ++f)
#pragma unroll
      for (int s = 0; s < SROW; ++s)
        acc[s] = __builtin_amdgcn_mfma_f32_16x16x32_f16(aq[s][f], bk[f], acc[s], 0, 0, 0);
#pragma unroll
    for (int s = 0; s < SROW; ++s)
#pragma unroll
      for (int r = 0; r < 4; ++r)
        rowmax[s * 4 + r] = fmaxf(rowmax[s * 4 + r], acc[s][r]);
  }
  // cross-lane max over the 16 key-lanes (bits 0-3); g bits untouched
#pragma unroll
  for (int d = 1; d < 16; d <<= 1)
#pragma unroll
    for (int i = 0; i < SROW * 4; ++i)
      rowmax[i] = fmaxf(rowmax[i], __shfl_xor(rowmax[i], d, 64));
  if (ln == 0) {
#pragma unroll
    for (int i = 0; i < SROW * 4; ++i)
      atomicMax(&lmax[(i >> 2) * 16 + g * 4 + (i & 3)], enc_f32(rowmax[i]));
  }
  __syncthreads();

  float th[SROW * 4];
#pragma unroll
  for (int i = 0; i < SROW * 4; ++i)
    th[i] = dec_f32(lmax[(i >> 2) * 16 + g * 4 + (i & 3)]) - EMIT_MARGIN;

  // ---- pass B: emit into LDS buffers (LDS atomics only) ----
  for (int sl = 0; sl < SLICES; ++sl) {
    half8 bk[4];
    loadB(sl, bk);
    f32x4v acc[SROW];
#pragma unroll
    for (int s = 0; s < SROW; ++s) acc[s] = f32x4v{0.f, 0.f, 0.f, 0.f};
#pragma unroll
    for (int f = 0; f < 4; ++f)
#pragma unroll
      for (int s = 0; s < SROW; ++s)
        acc[s] = __builtin_amdgcn_mfma_f32_16x16x32_f16(aq[s][f], bk[f], acc[s], 0, 0, 0);
    const int keyg = key0 + sl * 16 + ln;
#pragma unroll
    for (int s = 0; s < SROW; ++s)
#pragma unroll
      for (int r = 0; r < 4; ++r)
        if (acc[s][r] >= th[s * 4 + r]) {
          const int q = s * 16 + g * 4 + r;  // row within this 32-row tile
          const int slot = atomicAdd(&lcnt[q], 1);
          if (slot < BLOCKCAP) lbuf[q][slot] = pack16(keyg, acc[s][r]);
        }
  }
  __syncthreads();

  // ---- flush: fixed per-(query,chunk) region, plain stores ----
  const size_t qbase = (size_t)net * NQ + qt * QT;
  for (int j = tid; j < QT * BLOCKCAP; j += SCAN_WAVES * 64) {
    const int q = j >> 5, i = j & (BLOCKCAP - 1);
    const int c = lcnt[q];
    if (i < (c < BLOCKCAP ? c : BLOCKCAP))
      cand[((qbase + q) * NCHUNK + chunk) * BLOCKCAP + i] = lbuf[q][i];
  }
  if (tid < QT)
    cntb[(qbase + tid) * NCHUNK + chunk] = lcnt[tid];  // >BLOCKCAP => overflow
}

// ------------------------------- refine ------------------------------------
// one block (256 thr) per (query, net).  Gather ~160 packed candidates from
// the 32 chunk segments; global max from STORED fp16 scores; filter to
// survivors (>= max - SEL_MARGIN); exact fp32 scores for survivors only;
// exact softmax + PV.  Full-scan fallback if any segment overflowed.
__global__ __launch_bounds__(256)
void refine_kernel(const float* __restrict__ qcur, const float* __restrict__ emb,
                   const int* __restrict__ cntb, const unsigned* __restrict__ cand,
                   float* __restrict__ qnext) {
  const int q = blockIdx.x, net = blockIdx.y;
  const int tid = threadIdx.x, lane = tid & 63, w = tid >> 6;
  const int slot = net * NQ + q;
  __shared__ float qv[EDIM];
  __shared__ float osh[EDIM];
  __shared__ unsigned pr[NCHUNK * BLOCKCAP];
  __shared__ int offs[NCHUNK + 1];
  __shared__ int ovfl;
  __shared__ unsigned surv[4][64];
  __shared__ unsigned list[256];
  __shared__ float exsc[256];
  __shared__ int scnt[4];
  __shared__ float red[8];

  if (tid < EDIM) qv[tid] = 2.0f * qcur[(size_t)slot * EDIM + tid];
  if (tid == 0) {
    int o = 0, ov = 0;
    for (int c = 0; c < NCHUNK; ++c) {
      offs[c] = o;
      int cc = cntb[(size_t)slot * NCHUNK + c];
      if (cc > BLOCKCAP) { ov = 1; cc = BLOCKCAP; }
      o += cc;
    }
    offs[NCHUNK] = o;
    ovfl = ov;
  }
  __syncthreads();
  const int n = offs[NCHUNK];

  if (!ovfl) {
    // ---- gather segments into contiguous pr[0..n) ----
    for (int j = tid; j < NCHUNK * BLOCKCAP; j += 256) {
      const int c = j >> 5, i = j & (BLOCKCAP - 1);
      const int len = offs[c + 1] - offs[c];
      if (i < len)
        pr[offs[c] + i] = cand[((size_t)slot * NCHUNK + c) * BLOCKCAP + i];
    }
    __syncthreads();

    // ---- global max over stored fp16 scores ----
    float mx = -3.4e38f;
    for (int j = tid; j < n; j += 256) mx = fmaxf(mx, dec16(pr[j]));
#pragma unroll
    for (int d = 32; d; d >>= 1) mx = fmaxf(mx, __shfl_xor(mx, d, 64));
    if (lane == 0) red[w] = mx;
    __syncthreads();
    mx = fmaxf(fmaxf(red[0], red[1]), fmaxf(red[2], red[3]));
    const float th = mx - SEL_MARGIN;

    // ---- deterministic wave-striped compaction of survivors ----
    const int n4 = (n + 3) >> 2;
    const int lo = w * n4;
    const int hi = min(lo + n4, n);
    int c = 0;  // wave-uniform running count
    for (int base = lo; base < hi; base += 64) {
      const int j = base + lane;
      const bool p = (j < hi) && (dec16(pr[j]) >= th);
      const unsigned long long mb = __ballot(p);
      const int pos = c + __popcll(mb & ((1ull << lane) - 1));
      if (p && pos < 64) surv[w][pos] = pr[j];
      c += (int)__popcll(mb);
    }
    if (lane == 0) scnt[w] = c < 64 ? c : 64;
    __syncthreads();
    const int o1 = scnt[0], o2 = o1 + scnt[1], o3 = o2 + scnt[2];
    const int m = o3 + scnt[3];
    const int offw = (w == 0) ? 0 : (w == 1 ? o1 : (w == 2 ? o2 : o3));
    if (lane < scnt[w]) list[offw + lane] = surv[w][lane];
    __syncthreads();

    // ---- exact fp32 scores for the m survivors ----
    for (int j = w; j < m; j += 4) {
      const int ki = (int)(list[j] >> 16);
      const float* kr = emb + ((size_t)net * NKEY + ki) * ESTR;
      float p2 = qv[2 * lane] * kr[2 * lane] + qv[2 * lane + 1] * kr[2 * lane + 1];
#pragma unroll
      for (int d = 32; d; d >>= 1) p2 += __shfl_xor(p2, d, 64);
      if (lane == 0) exsc[j] = p2;
    }
    __syncthreads();
    if (w == 0) {
      float em = -3.4e38f;
      for (int j = lane; j < m; j += 64) em = fmaxf(em, exsc[j]);
#pragma unroll
      for (int d = 32; d; d >>= 1) em = fmaxf(em, __shfl_xor(em, d, 64));
      if (lane == 0) red[4] = em;
    }
    __syncthreads();
    const float em = red[4];
    for (int j = tid; j < m; j += 256) exsc[j] = expf(exsc[j] - em);
    __syncthreads();
    if (w == 0) {
      float l = 0.f;
      for (int j = lane; j < m; j += 64) l += exsc[j];
#pragma unroll
      for (int d = 32; d; d >>= 1) l += __shfl_xor(l, d, 64);
      if (lane == 0) red[5] = l;
    }
    __syncthreads();
    // ---- exact PV over survivors ----
    const float inv = 1.0f / red[5];
    const int e = tid & 127, hf = tid >> 7;
    float acc = 0.f;
    for (int j = hf; j < m; j += 2)
      acc += exsc[j] * emb[((size_t)net * NKEY + (int)(list[j] >> 16)) * ESTR + e];
    if (hf) osh[e] = acc;
    __syncthreads();
    if (!hf) qnext[(size_t)slot * EDIM + e] = (acc + osh[e]) * inv;
  } else {
    // ---- exact full-scan fallback (overflow only; ~1e-15) ----
    float mm = -3.4e38f;
    for (int j = w; j < NKEY; j += 4) {
      const float* kr = emb + ((size_t)net * NKEY + j) * ESTR;
      float p = qv[2 * lane] * kr[2 * lane] + qv[2 * lane + 1] * kr[2 * lane + 1];
#pragma unroll
      for (int d = 32; d; d >>= 1) p += __shfl_xor(p, d, 64);
      mm = fmaxf(mm, p);
    }
    if (lane == 0) red[w] = mm;
    __syncthreads();
    mm = fmaxf(fmaxf(red[0], red[1]), fmaxf(red[2], red[3]));
    if (tid < EDIM) osh[tid] = 0.f;
    if (tid == 0) red[4] = 0.f;
    __syncthreads();
    float lpart = 0.f;
    for (int j = w; j < NKEY; j += 4) {
      const float* kr = emb + ((size_t)net * NKEY + j) * ESTR;
      float p = qv[2 * lane] * kr[2 * lane] + qv[2 * lane + 1] * kr[2 * lane + 1];
#pragma unroll
      for (int d = 32; d; d >>= 1) p += __shfl_xor(p, d, 64);
      float ee = expf(p - mm);
      if (lane == 0) lpart += ee;
      atomicAdd(&osh[2 * lane], ee * kr[2 * lane]);
      atomicAdd(&osh[2 * lane + 1], ee * kr[2 * lane + 1]);
    }
    if (lane == 0) atomicAdd(&red[4], lpart);
    __syncthreads();
    if (tid < EDIM) qnext[(size_t)slot * EDIM + tid] = osh[tid] / red[4];
  }
}

// ------------------------------- head --------------------------------------
__global__ __launch_bounds__(64)
void head_kernel(const float* __restrict__ qf, const float* __restrict__ Wl,
                 const float* __restrict__ bl, float* __restrict__ out) {
  const int b = blockIdx.x, lane = threadIdx.x;
  float acc[10];
#pragma unroll
  for (int c = 0; c < 10; ++c) acc[c] = 0.f;
  for (int t = lane; t < NNET * EDIM; t += 64) {
    float z = qf[((size_t)(t >> 7) * NQ + b) * EDIM + (t & 127)];
    z = fmaxf(z, 0.f);
    const float* wr = Wl + t * 10;
#pragma unroll
    for (int c = 0; c < 10; ++c) acc[c] += z * wr[c];
  }
#pragma unroll
  for (int d = 32; d; d >>= 1)
#pragma unroll
    for (int c = 0; c < 10; ++c) acc[c] += __shfl_xor(acc[c], d, 64);
  if (lane == 0) {
    float lg[10], mxv = -3.4e38f;
#pragma unroll
    for (int c = 0; c < 10; ++c) {
      lg[c] = acc[c] + bl[c];
      mxv = fmaxf(mxv, lg[c]);
    }
    float s = 0.f;
#pragma unroll
    for (int c = 0; c < 10; ++c) s += expf(lg[c] - mxv);
    float lse = mxv + logf(s);
#pragma unroll
    for (int c = 0; c < 10; ++c) out[b * 10 + c] = lg[c] - lse;
  }
}

// ------------------------------- launch ------------------------------------
extern "C" void kernel_launch(void* const* d_in, const int* in_sizes, int n_in,
                              void* d_out, int out_size, void* d_ws, size_t ws_size,
                              hipStream_t stream) {
  (void)in_sizes; (void)n_in; (void)out_size;
  const float* x   = (const float*)d_in[0];
  const float* emb = (const float*)d_in[1];
  const float* We  = (const float*)d_in[2];
  const float* be  = (const float*)d_in[3];
  const float* Wl  = (const float*)d_in[4];
  const float* bl  = (const float*)d_in[5];
  float* out = (float*)d_out;

  char* p = (char*)d_ws;
  float* q0 = (float*)p;    p += (size_t)NNET * NQ * EDIM * 4;
  float* q1 = (float*)p;    p += (size_t)NNET * NQ * EDIM * 4;
  int* cntb = (int*)p;      p += (size_t)NNET * NQ * NCHUNK * 4;
  unsigned* cand = (unsigned*)p; p += (size_t)NNET * NQ * NCHUNK * BLOCKCAP * 4;
  _Float16* kh = (_Float16*)p;
  const bool f16k =
      ((size_t)(p - (char*)d_ws) + (size_t)NNET * NKEY * EDIM * 2) <= ws_size;

  enc_kernel<<<dim3(NQ), dim3(128), 0, stream>>>(x, We, be, q0);
  if (f16k)
    keyprep_kernel<<<dim3(4096), dim3(256), 0, stream>>>(emb, kh);

  float* qa = q0;
  float* qb = q1;
  for (int step = 0; step < 4; ++step) {
    if (f16k)
      scan_kernel<true><<<dim3(NNET * NCHUNK, NQ / QT), dim3(SCAN_WAVES * 64), 0, stream>>>(
          qa, emb, kh, cntb, cand);
    else
      scan_kernel<false><<<dim3(NNET * NCHUNK, NQ / QT), dim3(SCAN_WAVES * 64), 0, stream>>>(
          qa, emb, (const _Float16*)nullptr, cntb, cand);
    refine_kernel<<<dim3(NQ, NNET), dim3(256), 0, stream>>>(qa, emb, cntb, cand, qb);
    float* t = qa; qa = qb; qb = t;
  }
  head_kernel<<<dim3(NQ), dim3(64), 0, stream>>>(qa, Wl, bl, out);
}

// Round 8
// 346.925 us; speedup vs baseline: 77.3519x; 77.3519x over previous
//
#include <hip/hip_runtime.h>
#include <hip/hip_bf16.h>
#include <cstdint>
#include <cstddef>

// ---------------------------------------------------------------------------
// HopfieldModel: z = x@W_enc; 4x { q <- softmax(2 q K^T) K } per network;
// out = log_softmax(relu(concat q) @ W_lin + b_lin)
//
// scan (fp16 MFMA, two passes per 1024-key chunk):
//   pass A: chunk-local per-query max (LDS atomicMax).
//   pass B: emit packed (key<<16 | fp16 score) for s >= chunkmax - EMIT_MARGIN
//           into LDS, flush to fixed per-(query,chunk) region; ALSO store the
//           chunk max (cmaxb) so refine knows the true global max even when a
//           chunk overflows its 32 slots.
// refine: G = max over stored chunk maxes; chunks with cmax < G-9.75 are
//   provably irrelevant (skipped).  Relevant chunks: stored candidates
//   filtered at G-9.5, or -- if that chunk overflowed -- an exact fp32 rescan
//   of JUST that 1024-key chunk (round-7 lesson: the old all-32768-key
//   fallback was 16-48ms per straggler block and dominated the runtime).
//   Survivors (~10-60) exactly rescored in fp32, exact softmax + PV.
// ---------------------------------------------------------------------------

#define NNET 4
#define NQ   256
#define EDIM 128
#define NKEY 32768
#define ESTR 129              // embeddings row stride (col 128 dropped)
#define QT   32               // q rows per scan block
#define NCHUNK 32
#define KPC  (NKEY/NCHUNK)    // 1024 keys per chunk
#define SCAN_WAVES 4
#define KPW  (KPC/SCAN_WAVES) // 256 keys per wave
#define SLICES (KPW/16)       // 16 slices of 16 keys
#define SROW (QT/16)          // 2 row-tiles of 16 q rows
#define BLOCKCAP 32           // cand slots per (query, chunk)
#define SURV_CAP 512
#define EMIT_MARGIN 10.0f     // scan emission band below chunk max
#define SEL_MARGIN  9.5f      // stored-score filter below global max
#define REL_MARGIN  9.75f     // chunk relevance: cmax >= G - REL
#define RESCAN_MARGIN 10.0f   // exact-score filter for rescanned chunks

typedef _Float16 half8 __attribute__((ext_vector_type(8)));
typedef float f32x4v __attribute__((ext_vector_type(4)));

__device__ __forceinline__ float dec16(unsigned v) {
  _Float16 h = __builtin_bit_cast(_Float16, (unsigned short)(v & 0xFFFFu));
  return (float)h;
}
__device__ __forceinline__ unsigned pack16(int key, float s) {
  unsigned short hb = __builtin_bit_cast(unsigned short, (_Float16)s);
  return ((unsigned)key << 16) | (unsigned)hb;
}
__device__ __forceinline__ unsigned enc_f32(float f) {
  unsigned u = __float_as_uint(f);
  return (u & 0x80000000u) ? ~u : (u | 0x80000000u);  // order-preserving
}
__device__ __forceinline__ float dec_f32(unsigned e) {
  unsigned u = (e & 0x80000000u) ? (e & 0x7FFFFFFFu) : ~e;
  return __uint_as_float(u);
}

// --------------------------- encoder: z = x@We + be -------------------------
__global__ __launch_bounds__(128)
void enc_kernel(const float* __restrict__ x, const float* __restrict__ We,
                const float* __restrict__ be, float* __restrict__ q0) {
  const int b = blockIdx.x, tid = threadIdx.x;
  __shared__ float xs[784];
  for (int i = tid; i < 784; i += 128) xs[i] = x[b * 784 + i];
  __syncthreads();
  float acc = be[tid];
  for (int i = 0; i < 784; ++i) acc += xs[i] * We[i * EDIM + tid];
#pragma unroll
  for (int n = 0; n < NNET; ++n) q0[((size_t)n * NQ + b) * EDIM + tid] = acc;
}

// ------------------- keyprep: embeddings f32 -> fp16 (drop col 128) --------
typedef _Float16 half4v __attribute__((ext_vector_type(4)));
__global__ __launch_bounds__(256)
void keyprep_kernel(const float* __restrict__ emb, _Float16* __restrict__ kh) {
  const size_t quads = (size_t)NNET * NKEY * EDIM / 4;
  for (size_t i4 = (size_t)blockIdx.x * 256 + threadIdx.x; i4 < quads;
       i4 += (size_t)gridDim.x * 256) {
    const size_t row = i4 >> 5;
    const int col = (int)(i4 & 31) * 4;
    const float* src = emb + row * ESTR + col;
    half4v h;
#pragma unroll
    for (int j = 0; j < 4; ++j) h[j] = (_Float16)src[j];
    *(half4v*)(kh + i4 * 4) = h;
  }
}

// ------------------------------- scan --------------------------------------
// grid (128, 8): x = net*32+chunk, y = q-tile (32 rows).  256 threads =
// 4 waves, each wave owns 256 keys.
template <bool F16K>
__global__ __launch_bounds__(SCAN_WAVES * 64)
void scan_kernel(const float* __restrict__ qcur, const float* __restrict__ emb,
                 const _Float16* __restrict__ keysh,
                 int* __restrict__ cntb, float* __restrict__ cmaxb,
                 unsigned* __restrict__ cand) {
  const int nc = blockIdx.x;
  const int net = nc >> 5, chunk = nc & 31;
  const int qt = blockIdx.y;
  const int tid = threadIdx.x;
  const int lane = tid & 63;
  const int g = lane >> 4, ln = lane & 15;

  __shared__ unsigned lmax[QT];
  __shared__ int lcnt[QT];
  __shared__ unsigned lbuf[QT][BLOCKCAP];
  if (tid < QT) { lmax[tid] = enc_f32(-3.4e38f); lcnt[tid] = 0; }

  // Q A-fragments (16x16x32: lane holds row m=lane&15, k = 8*(lane>>4)+j),
  // beta=2 folded into q.
  half8 aq[SROW][4];
  {
    const float* qb = qcur + ((size_t)net * NQ + qt * QT) * EDIM;
#pragma unroll
    for (int s = 0; s < SROW; ++s)
#pragma unroll
      for (int f = 0; f < 4; ++f) {
        const float* p = qb + (s * 16 + ln) * EDIM + f * 32 + g * 8;
        half8 h;
#pragma unroll
        for (int j = 0; j < 8; ++j) h[j] = (_Float16)(2.0f * p[j]);
        aq[s][f] = h;
      }
  }
  __syncthreads();

  const int w = tid >> 6;
  const int key0 = chunk * KPC + w * KPW;

  auto loadB = [&](int sl, half8 bk[4]) {
    const size_t keyrow = (size_t)net * NKEY + key0 + sl * 16 + ln;
    if constexpr (F16K) {
      const _Float16* kp = keysh + keyrow * EDIM + g * 8;
#pragma unroll
      for (int f = 0; f < 4; ++f) bk[f] = *(const half8*)(kp + f * 32);
    } else {
      const float* kp = emb + keyrow * ESTR + g * 8;
#pragma unroll
      for (int f = 0; f < 4; ++f) {
        half8 h;
#pragma unroll
        for (int j = 0; j < 8; ++j) h[j] = (_Float16)kp[f * 32 + j];
        bk[f] = h;
      }
    }
  };

  // ---- pass A: chunk-local per-query max ----
  float rowmax[SROW * 4];
#pragma unroll
  for (int i = 0; i < SROW * 4; ++i) rowmax[i] = -3.4e38f;

  for (int sl = 0; sl < SLICES; ++sl) {
    half8 bk[4];
    loadB(sl, bk);
    f32x4v acc[SROW];
#pragma unroll
    for (int s = 0; s < SROW; ++s) acc[s] = f32x4v{0.f, 0.f, 0.f, 0.f};
#pragma unroll
    for (int f = 0; f < 4; ++f)
#pragma unroll
      for (int s = 0; s < SROW; ++s)
        acc[s] = __builtin_amdgcn_mfma_f32_16x16x32_f16(aq[s][f], bk[f], acc[s], 0, 0, 0);
#pragma unroll
    for (int s = 0; s < SROW; ++s)
#pragma unroll
      for (int r = 0; r < 4; ++r)
        rowmax[s * 4 + r] = fmaxf(rowmax[s * 4 + r], acc[s][r]);
  }
#pragma unroll
  for (int d = 1; d < 16; d <<= 1)
#pragma unroll
    for (int i = 0; i < SROW * 4; ++i)
      rowmax[i] = fmaxf(rowmax[i], __shfl_xor(rowmax[i], d, 64));
  if (ln == 0) {
#pragma unroll
    for (int i = 0; i < SROW * 4; ++i)
      atomicMax(&lmax[(i >> 2) * 16 + g * 4 + (i & 3)], enc_f32(rowmax[i]));
  }
  __syncthreads();

  float th[SROW * 4];
#pragma unroll
  for (int i = 0; i < SROW * 4; ++i)
    th[i] = dec_f32(lmax[(i >> 2) * 16 + g * 4 + (i & 3)]) - EMIT_MARGIN;

  // ---- pass B: emit into LDS buffers (LDS atomics only) ----
  for (int sl = 0; sl < SLICES; ++sl) {
    half8 bk[4];
    loadB(sl, bk);
    f32x4v acc[SROW];
#pragma unroll
    for (int s = 0; s < SROW; ++s) acc[s] = f32x4v{0.f, 0.f, 0.f, 0.f};
#pragma unroll
    for (int f = 0; f < 4; ++f)
#pragma unroll
      for (int s = 0; s < SROW; ++s)
        acc[s] = __builtin_amdgcn_mfma_f32_16x16x32_f16(aq[s][f], bk[f], acc[s], 0, 0, 0);
    const int keyg = key0 + sl * 16 + ln;
#pragma unroll
    for (int s = 0; s < SROW; ++s)
#pragma unroll
      for (int r = 0; r < 4; ++r)
        if (acc[s][r] >= th[s * 4 + r]) {
          const int q = s * 16 + g * 4 + r;  // row within this 32-row tile
          const int slot = atomicAdd(&lcnt[q], 1);
          if (slot < BLOCKCAP) lbuf[q][slot] = pack16(keyg, acc[s][r]);
        }
  }
  __syncthreads();

  // ---- flush: fixed per-(query,chunk) region, plain stores ----
  const size_t qbase = (size_t)net * NQ + qt * QT;
  for (int j = tid; j < QT * BLOCKCAP; j += SCAN_WAVES * 64) {
    const int q = j >> 5, i = j & (BLOCKCAP - 1);
    const int c = lcnt[q];
    if (i < (c < BLOCKCAP ? c : BLOCKCAP))
      cand[((qbase + q) * NCHUNK + chunk) * BLOCKCAP + i] = lbuf[q][i];
  }
  if (tid < QT) {
    cntb[(qbase + tid) * NCHUNK + chunk] = lcnt[tid];   // >BLOCKCAP => overflow
    cmaxb[(qbase + tid) * NCHUNK + chunk] = dec_f32(lmax[tid]);
  }
}

// ------------------------------- refine ------------------------------------
// one block (256 thr) per (query, net).  G = max stored chunk max; skip
// chunks with cmax < G-REL (provably irrelevant); stored-filter or per-chunk
// exact rescan (if overflowed); exact fp32 rescore of survivors; exact
// softmax + PV.
__global__ __launch_bounds__(256)
void refine_kernel(const float* __restrict__ qcur, const float* __restrict__ emb,
                   const int* __restrict__ cntb, const float* __restrict__ cmaxb,
                   const unsigned* __restrict__ cand, float* __restrict__ qnext) {
  const int q = blockIdx.x, net = blockIdx.y;
  const int tid = threadIdx.x, lane = tid & 63, w = tid >> 6;
  const int slot = net * NQ + q;
  __shared__ float qv[EDIM];
  __shared__ float osh[EDIM];
  __shared__ int ccnt[NCHUNK];
  __shared__ float cmax[NCHUNK];
  __shared__ int keys[SURV_CAP];
  __shared__ float exsc[SURV_CAP];
  __shared__ int nsurv;
  __shared__ float gmax_s;
  __shared__ float red[8];

  if (tid < EDIM) qv[tid] = 2.0f * qcur[(size_t)slot * EDIM + tid];
  if (tid < NCHUNK) {
    ccnt[tid] = cntb[(size_t)slot * NCHUNK + tid];
    cmax[tid] = cmaxb[(size_t)slot * NCHUNK + tid];
  }
  if (tid == 0) nsurv = 0;
  __syncthreads();
  if (tid == 0) {
    float gv = -3.4e38f;
    for (int c = 0; c < NCHUNK; ++c) gv = fmaxf(gv, cmax[c]);
    gmax_s = gv;
  }
  __syncthreads();
  const float G = gmax_s;

  // ---- collect survivors from relevant chunks ----
  for (int c = 0; c < NCHUNK; ++c) {
    if (cmax[c] < G - REL_MARGIN) continue;  // block-uniform: safe to skip
    const int cc = ccnt[c];
    if (cc <= BLOCKCAP) {
      if (tid < cc) {
        const unsigned pv = cand[((size_t)slot * NCHUNK + c) * BLOCKCAP + tid];
        if (dec16(pv) >= G - SEL_MARGIN) {
          const int i = atomicAdd(&nsurv, 1);
          if (i < SURV_CAP) keys[i] = (int)(pv >> 16);
        }
      }
    } else {
      // overflowed relevant chunk: exact fp32 rescan of its 1024 keys
      for (int k = c * KPC + tid; k < (c + 1) * KPC; k += 256) {
        const float* kr = emb + ((size_t)net * NKEY + k) * ESTR;
        float s = 0.f;
        for (int e = 0; e < EDIM; ++e) s += qv[e] * kr[e];
        if (s >= G - RESCAN_MARGIN) {
          const int i = atomicAdd(&nsurv, 1);
          if (i < SURV_CAP) keys[i] = k;
        }
      }
    }
  }
  __syncthreads();
  int m = nsurv < SURV_CAP ? nsurv : SURV_CAP;

  // ---- exact fp32 scores for the m survivors ----
  for (int j = w; j < m; j += 4) {
    const float* kr = emb + ((size_t)net * NKEY + keys[j]) * ESTR;
    float p2 = qv[2 * lane] * kr[2 * lane] + qv[2 * lane + 1] * kr[2 * lane + 1];
#pragma unroll
    for (int d = 32; d; d >>= 1) p2 += __shfl_xor(p2, d, 64);
    if (lane == 0) exsc[j] = p2;
  }
  __syncthreads();
  if (w == 0) {
    float em = -3.4e38f;
    for (int j = lane; j < m; j += 64) em = fmaxf(em, exsc[j]);
#pragma unroll
    for (int d = 32; d; d >>= 1) em = fmaxf(em, __shfl_xor(em, d, 64));
    if (lane == 0) red[0] = em;
  }
  __syncthreads();
  const float em = red[0];
  for (int j = tid; j < m; j += 256) exsc[j] = expf(exsc[j] - em);
  __syncthreads();
  if (w == 0) {
    float l = 0.f;
    for (int j = lane; j < m; j += 64) l += exsc[j];
#pragma unroll
    for (int d = 32; d; d >>= 1) l += __shfl_xor(l, d, 64);
    if (lane == 0) red[1] = l;
  }
  __syncthreads();
  // ---- exact PV over survivors ----
  const float inv = 1.0f / red[1];
  const int e = tid & 127, hf = tid >> 7;
  float acc = 0.f;
  for (int j = hf; j < m; j += 2)
    acc += exsc[j] * emb[((size_t)net * NKEY + keys[j]) * ESTR + e];
  if (hf) osh[e] = acc;
  __syncthreads();
  if (!hf) qnext[(size_t)slot * EDIM + e] = (acc + osh[e]) * inv;
}

// ------------------------------- head --------------------------------------
__global__ __launch_bounds__(64)
void head_kernel(const float* __restrict__ qf, const float* __restrict__ Wl,
                 const float* __restrict__ bl, float* __restrict__ out) {
  const int b = blockIdx.x, lane = threadIdx.x;
  float acc[10];
#pragma unroll
  for (int c = 0; c < 10; ++c) acc[c] = 0.f;
  for (int t = lane; t < NNET * EDIM; t += 64) {
    float z = qf[((size_t)(t >> 7) * NQ + b) * EDIM + (t & 127)];
    z = fmaxf(z, 0.f);
    const float* wr = Wl + t * 10;
#pragma unroll
    for (int c = 0; c < 10; ++c) acc[c] += z * wr[c];
  }
#pragma unroll
  for (int d = 32; d; d >>= 1)
#pragma unroll
    for (int c = 0; c < 10; ++c) acc[c] += __shfl_xor(acc[c], d, 64);
  if (lane == 0) {
    float lg[10], mxv = -3.4e38f;
#pragma unroll
    for (int c = 0; c < 10; ++c) {
      lg[c] = acc[c] + bl[c];
      mxv = fmaxf(mxv, lg[c]);
    }
    float s = 0.f;
#pragma unroll
    for (int c = 0; c < 10; ++c) s += expf(lg[c] - mxv);
    float lse = mxv + logf(s);
#pragma unroll
    for (int c = 0; c < 10; ++c) out[b * 10 + c] = lg[c] - lse;
  }
}

// ------------------------------- launch ------------------------------------
extern "C" void kernel_launch(void* const* d_in, const int* in_sizes, int n_in,
                              void* d_out, int out_size, void* d_ws, size_t ws_size,
                              hipStream_t stream) {
  (void)in_sizes; (void)n_in; (void)out_size;
  const float* x   = (const float*)d_in[0];
  const float* emb = (const float*)d_in[1];
  const float* We  = (const float*)d_in[2];
  const float* be  = (const float*)d_in[3];
  const float* Wl  = (const float*)d_in[4];
  const float* bl  = (const float*)d_in[5];
  float* out = (float*)d_out;

  char* p = (char*)d_ws;
  float* q0 = (float*)p;    p += (size_t)NNET * NQ * EDIM * 4;
  float* q1 = (float*)p;    p += (size_t)NNET * NQ * EDIM * 4;
  int* cntb = (int*)p;      p += (size_t)NNET * NQ * NCHUNK * 4;
  float* cmaxb = (float*)p; p += (size_t)NNET * NQ * NCHUNK * 4;
  unsigned* cand = (unsigned*)p; p += (size_t)NNET * NQ * NCHUNK * BLOCKCAP * 4;
  _Float16* kh = (_Float16*)p;
  const bool f16k =
      ((size_t)(p - (char*)d_ws) + (size_t)NNET * NKEY * EDIM * 2) <= ws_size;

  enc_kernel<<<dim3(NQ), dim3(128), 0, stream>>>(x, We, be, q0);
  if (f16k)
    keyprep_kernel<<<dim3(4096), dim3(256), 0, stream>>>(emb, kh);

  float* qa = q0;
  float* qb = q1;
  for (int step = 0; step < 4; ++step) {
    if (f16k)
      scan_kernel<true><<<dim3(NNET * NCHUNK, NQ / QT), dim3(SCAN_WAVES * 64), 0, stream>>>(
          qa, emb, kh, cntb, cmaxb, cand);
    else
      scan_kernel<false><<<dim3(NNET * NCHUNK, NQ / QT), dim3(SCAN_WAVES * 64), 0, stream>>>(
          qa, emb, (const _Float16*)nullptr, cntb, cmaxb, cand);
    refine_kernel<<<dim3(NQ, NNET), dim3(256), 0, stream>>>(qa, emb, cntb, cmaxb, cand, qb);
    float* t = qa; qa = qb; qb = t;
  }
  head_kernel<<<dim3(NQ), dim3(64), 0, stream>>>(qa, Wl, bl, out);
}

// Round 9
// 345.883 us; speedup vs baseline: 77.5850x; 1.0030x over previous
//
#include <hip/hip_runtime.h>
#include <hip/hip_bf16.h>
#include <cstdint>
#include <cstddef>

// ---------------------------------------------------------------------------
// HopfieldModel: z = x@W_enc; 4x { q <- softmax(2 q K^T) K } per network;
// out = log_softmax(relu(concat q) @ W_lin + b_lin)
//
// scan (fp16 MFMA, SINGLE pass per 1024-key chunk): score all 16 slices into
// register-resident accumulators (acc[16][2] f32x4 = 128 VGPR), butterfly +
// LDS atomicMax for the chunk-local per-query max, then emit packed
// (key<<16 | fp16 score) for s >= chunkmax - EMIT_MARGIN straight FROM
// REGISTERS (round-8 lesson: the 2-pass variant at VGPR=48 had zero ILP --
// every slice was a bare load->stall->MFMA chain, 71us vs ~10us floor).
// Also stores the chunk max (cmaxb) so refine knows the global max even if
// a chunk overflows its 32 slots.
// refine: G = max stored chunk max; chunks with cmax < G-9.75 provably
// irrelevant (skipped); stored candidates filtered at G-9.5; overflowed
// relevant chunks get an exact fp32 rescan of JUST that chunk (round-7
// lesson); survivors exactly rescored fp32, exact softmax + PV.
// ---------------------------------------------------------------------------

#define NNET 4
#define NQ   256
#define EDIM 128
#define NKEY 32768
#define ESTR 129              // embeddings row stride (col 128 dropped)
#define QT   32               // q rows per scan block
#define NCHUNK 32
#define KPC  (NKEY/NCHUNK)    // 1024 keys per chunk
#define SCAN_WAVES 4
#define KPW  (KPC/SCAN_WAVES) // 256 keys per wave
#define SLICES (KPW/16)       // 16 slices of 16 keys
#define LGRP 2                // slices per load batch (ILP)
#define SROW (QT/16)          // 2 row-tiles of 16 q rows
#define BLOCKCAP 32           // cand slots per (query, chunk)
#define SURV_CAP 512
#define EMIT_MARGIN 10.0f     // scan emission band below chunk max
#define SEL_MARGIN  9.5f      // stored-score filter below global max
#define REL_MARGIN  9.75f     // chunk relevance: cmax >= G - REL
#define RESCAN_MARGIN 10.0f   // exact-score filter for rescanned chunks

typedef _Float16 half8 __attribute__((ext_vector_type(8)));
typedef float f32x4v __attribute__((ext_vector_type(4)));

__device__ __forceinline__ float dec16(unsigned v) {
  _Float16 h = __builtin_bit_cast(_Float16, (unsigned short)(v & 0xFFFFu));
  return (float)h;
}
__device__ __forceinline__ unsigned pack16(int key, float s) {
  unsigned short hb = __builtin_bit_cast(unsigned short, (_Float16)s);
  return ((unsigned)key << 16) | (unsigned)hb;
}
__device__ __forceinline__ unsigned enc_f32(float f) {
  unsigned u = __float_as_uint(f);
  return (u & 0x80000000u) ? ~u : (u | 0x80000000u);  // order-preserving
}
__device__ __forceinline__ float dec_f32(unsigned e) {
  unsigned u = (e & 0x80000000u) ? (e & 0x7FFFFFFFu) : ~e;
  return __uint_as_float(u);
}

// --------------------------- encoder: z = x@We + be -------------------------
__global__ __launch_bounds__(128)
void enc_kernel(const float* __restrict__ x, const float* __restrict__ We,
                const float* __restrict__ be, float* __restrict__ q0) {
  const int b = blockIdx.x, tid = threadIdx.x;
  __shared__ float xs[784];
  for (int i = tid; i < 784; i += 128) xs[i] = x[b * 784 + i];
  __syncthreads();
  float acc = be[tid];
  for (int i = 0; i < 784; ++i) acc += xs[i] * We[i * EDIM + tid];
#pragma unroll
  for (int n = 0; n < NNET; ++n) q0[((size_t)n * NQ + b) * EDIM + tid] = acc;
}

// ------------------- keyprep: embeddings f32 -> fp16 (drop col 128) --------
typedef _Float16 half4v __attribute__((ext_vector_type(4)));
__global__ __launch_bounds__(256)
void keyprep_kernel(const float* __restrict__ emb, _Float16* __restrict__ kh) {
  const size_t quads = (size_t)NNET * NKEY * EDIM / 4;
  for (size_t i4 = (size_t)blockIdx.x * 256 + threadIdx.x; i4 < quads;
       i4 += (size_t)gridDim.x * 256) {
    const size_t row = i4 >> 5;
    const int col = (int)(i4 & 31) * 4;
    const float* src = emb + row * ESTR + col;
    half4v h;
#pragma unroll
    for (int j = 0; j < 4; ++j) h[j] = (_Float16)src[j];
    *(half4v*)(kh + i4 * 4) = h;
  }
}

// ------------------------------- scan --------------------------------------
// grid (128, 8): x = net*32+chunk, y = q-tile (32 rows).  256 threads =
// 4 waves, each wave owns 256 keys.  Single pass, register-resident scores.
template <bool F16K>
__global__ __launch_bounds__(SCAN_WAVES * 64)
void scan_kernel(const float* __restrict__ qcur, const float* __restrict__ emb,
                 const _Float16* __restrict__ keysh,
                 int* __restrict__ cntb, float* __restrict__ cmaxb,
                 unsigned* __restrict__ cand) {
  const int nc = blockIdx.x;
  const int net = nc >> 5, chunk = nc & 31;
  const int qt = blockIdx.y;
  const int tid = threadIdx.x;
  const int lane = tid & 63;
  const int g = lane >> 4, ln = lane & 15;

  __shared__ unsigned lmax[QT];
  __shared__ int lcnt[QT];
  __shared__ unsigned lbuf[QT][BLOCKCAP];
  if (tid < QT) { lmax[tid] = enc_f32(-3.4e38f); lcnt[tid] = 0; }

  // Q A-fragments (16x16x32: lane holds row m=lane&15, k = 8*(lane>>4)+j),
  // beta=2 folded into q.
  half8 aq[SROW][4];
  {
    const float* qb = qcur + ((size_t)net * NQ + qt * QT) * EDIM;
#pragma unroll
    for (int s = 0; s < SROW; ++s)
#pragma unroll
      for (int f = 0; f < 4; ++f) {
        const float* p = qb + (s * 16 + ln) * EDIM + f * 32 + g * 8;
        half8 h;
#pragma unroll
        for (int j = 0; j < 8; ++j) h[j] = (_Float16)(2.0f * p[j]);
        aq[s][f] = h;
      }
  }
  __syncthreads();

  const int w = tid >> 6;
  const int key0 = chunk * KPC + w * KPW;

  auto loadB = [&](int sl, half8 bk[4]) {
    const size_t keyrow = (size_t)net * NKEY + key0 + sl * 16 + ln;
    if constexpr (F16K) {
      const _Float16* kp = keysh + keyrow * EDIM + g * 8;
#pragma unroll
      for (int f = 0; f < 4; ++f) bk[f] = *(const half8*)(kp + f * 32);
    } else {
      const float* kp = emb + keyrow * ESTR + g * 8;
#pragma unroll
      for (int f = 0; f < 4; ++f) {
        half8 h;
#pragma unroll
        for (int j = 0; j < 8; ++j) h[j] = (_Float16)kp[f * 32 + j];
        bk[f] = h;
      }
    }
  };

  // ---- single scoring pass: all slice accumulators stay in registers ----
  f32x4v acc[SLICES][SROW];
#pragma unroll
  for (int b = 0; b < SLICES; b += LGRP) {
    half8 bk[LGRP][4];
#pragma unroll
    for (int u = 0; u < LGRP; ++u) loadB(b + u, bk[u]);   // LGRP*4 loads in flight
#pragma unroll
    for (int u = 0; u < LGRP; ++u) {
#pragma unroll
      for (int s = 0; s < SROW; ++s) acc[b + u][s] = f32x4v{0.f, 0.f, 0.f, 0.f};
#pragma unroll
      for (int f = 0; f < 4; ++f)
#pragma unroll
        for (int s = 0; s < SROW; ++s)
          acc[b + u][s] =
              __builtin_amdgcn_mfma_f32_16x16x32_f16(aq[s][f], bk[u][f], acc[b + u][s], 0, 0, 0);
    }
  }

  // ---- chunk-local per-query max (C layout: row = 4*g + r, col = key) ----
  float rowmax[SROW * 4];
#pragma unroll
  for (int i = 0; i < SROW * 4; ++i) rowmax[i] = -3.4e38f;
#pragma unroll
  for (int sl = 0; sl < SLICES; ++sl)
#pragma unroll
    for (int s = 0; s < SROW; ++s)
#pragma unroll
      for (int r = 0; r < 4; ++r)
        rowmax[s * 4 + r] = fmaxf(rowmax[s * 4 + r], acc[sl][s][r]);
#pragma unroll
  for (int d = 1; d < 16; d <<= 1)
#pragma unroll
    for (int i = 0; i < SROW * 4; ++i)
      rowmax[i] = fmaxf(rowmax[i], __shfl_xor(rowmax[i], d, 64));
  if (ln == 0) {
#pragma unroll
    for (int i = 0; i < SROW * 4; ++i)
      atomicMax(&lmax[(i >> 2) * 16 + g * 4 + (i & 3)], enc_f32(rowmax[i]));
  }
  __syncthreads();

  float th[SROW * 4];
#pragma unroll
  for (int i = 0; i < SROW * 4; ++i)
    th[i] = dec_f32(lmax[(i >> 2) * 16 + g * 4 + (i & 3)]) - EMIT_MARGIN;

  // ---- emit from registers (no reload, no re-MFMA) ----
#pragma unroll
  for (int sl = 0; sl < SLICES; ++sl) {
    const int keyg = key0 + sl * 16 + ln;
#pragma unroll
    for (int s = 0; s < SROW; ++s)
#pragma unroll
      for (int r = 0; r < 4; ++r)
        if (acc[sl][s][r] >= th[s * 4 + r]) {
          const int q = s * 16 + g * 4 + r;  // row within this 32-row tile
          const int slot = atomicAdd(&lcnt[q], 1);
          if (slot < BLOCKCAP) lbuf[q][slot] = pack16(keyg, acc[sl][s][r]);
        }
  }
  __syncthreads();

  // ---- flush: fixed per-(query,chunk) region, plain stores ----
  const size_t qbase = (size_t)net * NQ + qt * QT;
  for (int j = tid; j < QT * BLOCKCAP; j += SCAN_WAVES * 64) {
    const int q = j >> 5, i = j & (BLOCKCAP - 1);
    const int c = lcnt[q];
    if (i < (c < BLOCKCAP ? c : BLOCKCAP))
      cand[((qbase + q) * NCHUNK + chunk) * BLOCKCAP + i] = lbuf[q][i];
  }
  if (tid < QT) {
    cntb[(qbase + tid) * NCHUNK + chunk] = lcnt[tid];   // >BLOCKCAP => overflow
    cmaxb[(qbase + tid) * NCHUNK + chunk] = dec_f32(lmax[tid]);
  }
}

// ------------------------------- refine ------------------------------------
// one block (256 thr) per (query, net).  G = max stored chunk max; skip
// chunks with cmax < G-REL (provably irrelevant); stored-filter or per-chunk
// exact rescan (if overflowed); exact fp32 rescore of survivors; exact
// softmax + PV.
__global__ __launch_bounds__(256)
void refine_kernel(const float* __restrict__ qcur, const float* __restrict__ emb,
                   const int* __restrict__ cntb, const float* __restrict__ cmaxb,
                   const unsigned* __restrict__ cand, float* __restrict__ qnext) {
  const int q = blockIdx.x, net = blockIdx.y;
  const int tid = threadIdx.x, lane = tid & 63, w = tid >> 6;
  const int slot = net * NQ + q;
  __shared__ float qv[EDIM];
  __shared__ float osh[EDIM];
  __shared__ int ccnt[NCHUNK];
  __shared__ float cmax[NCHUNK];
  __shared__ int keys[SURV_CAP];
  __shared__ float exsc[SURV_CAP];
  __shared__ int nsurv;
  __shared__ float gmax_s;
  __shared__ float red[8];

  if (tid < EDIM) qv[tid] = 2.0f * qcur[(size_t)slot * EDIM + tid];
  if (tid < NCHUNK) {
    ccnt[tid] = cntb[(size_t)slot * NCHUNK + tid];
    cmax[tid] = cmaxb[(size_t)slot * NCHUNK + tid];
  }
  if (tid == 0) nsurv = 0;
  __syncthreads();
  if (tid == 0) {
    float gv = -3.4e38f;
    for (int c = 0; c < NCHUNK; ++c) gv = fmaxf(gv, cmax[c]);
    gmax_s = gv;
  }
  __syncthreads();
  const float G = gmax_s;

  // ---- collect survivors from relevant chunks ----
  for (int c = 0; c < NCHUNK; ++c) {
    if (cmax[c] < G - REL_MARGIN) continue;  // block-uniform: safe to skip
    const int cc = ccnt[c];
    if (cc <= BLOCKCAP) {
      if (tid < cc) {
        const unsigned pv = cand[((size_t)slot * NCHUNK + c) * BLOCKCAP + tid];
        if (dec16(pv) >= G - SEL_MARGIN) {
          const int i = atomicAdd(&nsurv, 1);
          if (i < SURV_CAP) keys[i] = (int)(pv >> 16);
        }
      }
    } else {
      // overflowed relevant chunk: exact fp32 rescan of its 1024 keys
      for (int k = c * KPC + tid; k < (c + 1) * KPC; k += 256) {
        const float* kr = emb + ((size_t)net * NKEY + k) * ESTR;
        float s = 0.f;
        for (int e = 0; e < EDIM; ++e) s += qv[e] * kr[e];
        if (s >= G - RESCAN_MARGIN) {
          const int i = atomicAdd(&nsurv, 1);
          if (i < SURV_CAP) keys[i] = k;
        }
      }
    }
  }
  __syncthreads();
  int m = nsurv < SURV_CAP ? nsurv : SURV_CAP;

  // ---- exact fp32 scores for the m survivors ----
  for (int j = w; j < m; j += 4) {
    const float* kr = emb + ((size_t)net * NKEY + keys[j]) * ESTR;
    float p2 = qv[2 * lane] * kr[2 * lane] + qv[2 * lane + 1] * kr[2 * lane + 1];
#pragma unroll
    for (int d = 32; d; d >>= 1) p2 += __shfl_xor(p2, d, 64);
    if (lane == 0) exsc[j] = p2;
  }
  __syncthreads();
  if (w == 0) {
    float em = -3.4e38f;
    for (int j = lane; j < m; j += 64) em = fmaxf(em, exsc[j]);
#pragma unroll
    for (int d = 32; d; d >>= 1) em = fmaxf(em, __shfl_xor(em, d, 64));
    if (lane == 0) red[0] = em;
  }
  __syncthreads();
  const float em = red[0];
  for (int j = tid; j < m; j += 256) exsc[j] = expf(exsc[j] - em);
  __syncthreads();
  if (w == 0) {
    float l = 0.f;
    for (int j = lane; j < m; j += 64) l += exsc[j];
#pragma unroll
    for (int d = 32; d; d >>= 1) l += __shfl_xor(l, d, 64);
    if (lane == 0) red[1] = l;
  }
  __syncthreads();
  // ---- exact PV over survivors ----
  const float inv = 1.0f / red[1];
  const int e = tid & 127, hf = tid >> 7;
  float acc = 0.f;
  for (int j = hf; j < m; j += 2)
    acc += exsc[j] * emb[((size_t)net * NKEY + keys[j]) * ESTR + e];
  if (hf) osh[e] = acc;
  __syncthreads();
  if (!hf) qnext[(size_t)slot * EDIM + e] = (acc + osh[e]) * inv;
}

// ------------------------------- head --------------------------------------
__global__ __launch_bounds__(64)
void head_kernel(const float* __restrict__ qf, const float* __restrict__ Wl,
                 const float* __restrict__ bl, float* __restrict__ out) {
  const int b = blockIdx.x, lane = threadIdx.x;
  float acc[10];
#pragma unroll
  for (int c = 0; c < 10; ++c) acc[c] = 0.f;
  for (int t = lane; t < NNET * EDIM; t += 64) {
    float z = qf[((size_t)(t >> 7) * NQ + b) * EDIM + (t & 127)];
    z = fmaxf(z, 0.f);
    const float* wr = Wl + t * 10;
#pragma unroll
    for (int c = 0; c < 10; ++c) acc[c] += z * wr[c];
  }
#pragma unroll
  for (int d = 32; d; d >>= 1)
#pragma unroll
    for (int c = 0; c < 10; ++c) acc[c] += __shfl_xor(acc[c], d, 64);
  if (lane == 0) {
    float lg[10], mxv = -3.4e38f;
#pragma unroll
    for (int c = 0; c < 10; ++c) {
      lg[c] = acc[c] + bl[c];
      mxv = fmaxf(mxv, lg[c]);
    }
    float s = 0.f;
#pragma unroll
    for (int c = 0; c < 10; ++c) s += expf(lg[c] - mxv);
    float lse = mxv + logf(s);
#pragma unroll
    for (int c = 0; c < 10; ++c) out[b * 10 + c] = lg[c] - lse;
  }
}

// ------------------------------- launch ------------------------------------
extern "C" void kernel_launch(void* const* d_in, const int* in_sizes, int n_in,
                              void* d_out, int out_size, void* d_ws, size_t ws_size,
                              hipStream_t stream) {
  (void)in_sizes; (void)n_in; (void)out_size;
  const float* x   = (const float*)d_in[0];
  const float* emb = (const float*)d_in[1];
  const float* We  = (const float*)d_in[2];
  const float* be  = (const float*)d_in[3];
  const float* Wl  = (const float*)d_in[4];
  const float* bl  = (const float*)d_in[5];
  float* out = (float*)d_out;

  char* p = (char*)d_ws;
  float* q0 = (float*)p;    p += (size_t)NNET * NQ * EDIM * 4;
  float* q1 = (float*)p;    p += (size_t)NNET * NQ * EDIM * 4;
  int* cntb = (int*)p;      p += (size_t)NNET * NQ * NCHUNK * 4;
  float* cmaxb = (float*)p; p += (size_t)NNET * NQ * NCHUNK * 4;
  unsigned* cand = (unsigned*)p; p += (size_t)NNET * NQ * NCHUNK * BLOCKCAP * 4;
  _Float16* kh = (_Float16*)p;
  const bool f16k =
      ((size_t)(p - (char*)d_ws) + (size_t)NNET * NKEY * EDIM * 2) <= ws_size;

  enc_kernel<<<dim3(NQ), dim3(128), 0, stream>>>(x, We, be, q0);
  if (f16k)
    keyprep_kernel<<<dim3(4096), dim3(256), 0, stream>>>(emb, kh);

  float* qa = q0;
  float* qb = q1;
  for (int step = 0; step < 4; ++step) {
    if (f16k)
      scan_kernel<true><<<dim3(NNET * NCHUNK, NQ / QT), dim3(SCAN_WAVES * 64), 0, stream>>>(
          qa, emb, kh, cntb, cmaxb, cand);
    else
      scan_kernel<false><<<dim3(NNET * NCHUNK, NQ / QT), dim3(SCAN_WAVES * 64), 0, stream>>>(
          qa, emb, (const _Float16*)nullptr, cntb, cmaxb, cand);
    refine_kernel<<<dim3(NQ, NNET), dim3(256), 0, stream>>>(qa, emb, cntb, cmaxb, cand, qb);
    float* t = qa; qa = qb; qb = t;
  }
  head_kernel<<<dim3(NQ), dim3(64), 0, stream>>>(qa, Wl, bl, out);
}